// Round 1
// baseline (561.510 us; speedup 1.0000x reference)
//
#include <hip/hip_runtime.h>

// Problem constants (fixed by setup_inputs).
#define N_SAMP 80
#define C_CH   2048
#define HW     256          // 16*16
#define S_TOP  512
#define HW4    64           // HW / 4 (float4 per channel)

typedef float vfloat4 __attribute__((ext_vector_type(4)));

// ---------------------------------------------------------------------------
// Kernel 1: rank-by-counting (replaces 66-stage bitonic sort).
// key = (monotone float bits << 11) | (2047 - idx)  -- same packed key as
// before: descending order == score desc, index asc on ties (jax.lax.top_k).
// rank(i) = #{ j : key_j > key_i }.  Channel i is in the top-512 iff
// rank(i) < 512, and its position k in the topk list IS rank(i).
//
// Layout: 640 blocks x 256 threads; block handles row n = blockIdx>>3,
// channel chunk (blockIdx&7)*256.  One thread = one channel i.
// The j-loop address s_ca[n*2048+j] is wave-uniform -> scalar loads + SALU
// key build; per-j vector work is ~2 VALU (v_cmp_gt_u64 + addc).
// No LDS, no barriers, all 256 CUs busy.
// ---------------------------------------------------------------------------
__global__ __launch_bounds__(256) void rank_count_kernel(
    const float* __restrict__ s_ca, int* __restrict__ rank) {
  const int n = blockIdx.x >> 3;
  const int i = ((blockIdx.x & 7) << 8) | threadIdx.x;
  const float* __restrict__ row = s_ca + (size_t)n * C_CH;

  unsigned int bi = __float_as_uint(row[i]);
  bi ^= (bi & 0x80000000u) ? 0xFFFFFFFFu : 0x80000000u;
  const unsigned long long ki =
      ((unsigned long long)bi << 11) | (unsigned long long)(C_CH - 1 - i);

  int cnt = 0;
#pragma unroll 8
  for (int j = 0; j < C_CH; ++j) {
    unsigned int bj = __float_as_uint(row[j]);  // uniform addr -> s_load
    bj ^= (bj & 0x80000000u) ? 0xFFFFFFFFu : 0x80000000u;
    const unsigned long long kj =
        ((unsigned long long)bj << 11) | (unsigned long long)(C_CH - 1 - j);
    cnt += (kj > ki) ? 1 : 0;
  }
  rank[(size_t)n * C_CH + i] = (cnt < S_TOP) ? cnt : -1;
}

// ---------------------------------------------------------------------------
// Kernel 2: fused output. Each 64-lane wave owns ONE (n, ch) pair and
// produces BOTH the plain output row and the aug output row:
//   plain: x[n,ch,:] * s[n,ch]
//   aug  : ch in topk(n) at rank k ?
//          (0.7*x[n,ch,:] + 0.3*x[j(n), rand_index[n,k], :]) * s : x*s
// x[n,ch,:] is read ONCE (was read twice by separate plain/aug blocks).
// s_ca / rank / partner / rand_index are wave-uniform -> scalar loads;
// the k>=0 branch is wave-uniform (no divergence).
// Nontemporal stores keep the 335 MB output from evicting x out of L3 so
// the random partner-channel gather stays cache-resident.
// ---------------------------------------------------------------------------
__global__ __launch_bounds__(256) void shuffle_out_fused(
    const float4* __restrict__ x4, const float* __restrict__ s_ca,
    const int* __restrict__ rand_index, const int* __restrict__ partner,
    const int* __restrict__ rank, float4* __restrict__ out4) {
  const unsigned int lane = threadIdx.x & 63u;
  const unsigned int pw = blockIdx.x * 4u + (threadIdx.x >> 6);  // (n,ch) id
  const unsigned int n = pw >> 11;
  const unsigned int ch = pw & 2047u;
  const unsigned int g = n >> 4;   // way group
  const unsigned int b = n & 15u;  // index within group

  // out m-index: plain = g*32 + b, aug = g*32 + 16 + b
  const size_t out_plain =
      (((size_t)((g << 5) | b) * C_CH + ch) << 6) | lane;
  const size_t out_aug = out_plain + ((size_t)(16 * C_CH) << 6);

  const float s = s_ca[pw];                       // wave-uniform
  const float4 v = x4[((size_t)pw << 6) | lane];  // coalesced 16B/lane
  float4 pv = make_float4(v.x * s, v.y * s, v.z * s, v.w * s);
  float4 av = pv;

  const int k = rank[pw];  // wave-uniform
  if (k >= 0) {            // wave-uniform branch
    int jn = (int)n + 1 + partner[n];
    if (jn >= N_SAMP) jn -= N_SAMP;
    const int pc = rand_index[(size_t)n * S_TOP + k];
    const float4 u = x4[((((size_t)jn << 11) | (size_t)pc) << 6) | lane];
    av.x = (0.7f * v.x + 0.3f * u.x) * s;
    av.y = (0.7f * v.y + 0.3f * u.y) * s;
    av.z = (0.7f * v.z + 0.3f * u.z) * s;
    av.w = (0.7f * v.w + 0.3f * u.w) * s;
  }

  __builtin_nontemporal_store(*(const vfloat4*)&pv,
                              (vfloat4*)&out4[out_plain]);
  __builtin_nontemporal_store(*(const vfloat4*)&av,
                              (vfloat4*)&out4[out_aug]);
}

extern "C" void kernel_launch(void* const* d_in, const int* in_sizes, int n_in,
                              void* d_out, int out_size, void* d_ws,
                              size_t ws_size, hipStream_t stream) {
  const float* x = (const float*)d_in[0];
  const float* s_ca = (const float*)d_in[1];
  const int* rand_index = (const int*)d_in[2];
  const int* partner = (const int*)d_in[3];
  // d_in[4] = shuffle_num (512, fixed by setup)

  int* rank = (int*)d_ws;  // N_SAMP * C_CH ints = 655,360 B

  rank_count_kernel<<<N_SAMP * 8, 256, 0, stream>>>(s_ca, rank);

  // One wave per (n, ch): 80*2048 = 163,840 waves = 40,960 blocks of 256.
  const int nblocks = (N_SAMP * C_CH) / 4;
  shuffle_out_fused<<<nblocks, 256, 0, stream>>>(
      (const float4*)x, s_ca, rand_index, partner, rank, (float4*)d_out);
}

// Round 3
// 478.059 us; speedup vs baseline: 1.1746x; 1.1746x over previous
//
#include <hip/hip_runtime.h>

// Problem constants (fixed by setup_inputs).
#define N_SAMP 80
#define C_CH   2048
#define HW     256          // 16*16
#define S_TOP  512
#define HW4    64           // HW / 4 (float4 per channel)

// ---------------------------------------------------------------------------
// Kernel 1: rank-by-counting with LDS-staged keys.
// key = (monotone float bits << 11) | (2047 - idx): descending order ==
// score desc, index asc on ties (exact jax.lax.top_k semantics; keys unique).
// rank(i) = #{ j : key_j > key_i }; channel i is in top-512 iff rank < 512,
// and its topk position k IS rank(i).
//
// 640 blocks (8 per row n); each block stages the full row's 2048 packed
// keys in LDS (16 KiB), then each of 256 threads owns one channel i and
// loops j over LDS. keys[j] is wave-uniform per iteration -> LDS broadcast
// (no bank conflicts, no reliance on compiler scalar-ization).
// ~2 VALU + 1 ds_read per iter, 2.5 blocks/CU -> VALU-bound, ~10 us.
// ---------------------------------------------------------------------------
__global__ __launch_bounds__(256) void rank_lds_kernel(
    const float* __restrict__ s_ca, int* __restrict__ rank) {
  __shared__ unsigned long long keys[C_CH];
  const int n = blockIdx.x >> 3;
  const int tid = threadIdx.x;
  const float* __restrict__ row = s_ca + (size_t)n * C_CH;

  for (int i = tid; i < C_CH; i += 256) {
    unsigned int b = __float_as_uint(row[i]);
    b ^= (b & 0x80000000u) ? 0xFFFFFFFFu : 0x80000000u;
    keys[i] = ((unsigned long long)b << 11) |
              (unsigned long long)(C_CH - 1 - i);
  }
  __syncthreads();

  const int i = ((blockIdx.x & 7) << 8) | tid;
  const unsigned long long ki = keys[i];
  int cnt = 0;
#pragma unroll 16
  for (int j = 0; j < C_CH; ++j) {
    cnt += (keys[j] > ki) ? 1 : 0;
  }
  rank[(size_t)n * C_CH + i] = (cnt < S_TOP) ? cnt : -1;
}

// ---------------------------------------------------------------------------
// Kernel 2: fused output (plain stores — NT hint reverted, it was the
// round-1 regression suspect on the dominant 335 MB write stream).
// Each 64-lane wave owns ONE (n, ch) pair and produces BOTH output rows:
//   plain: x[n,ch,:] * s[n,ch]
//   aug  : ch in topk(n) at rank k ?
//          (0.7*x[n,ch,:] + 0.3*x[j(n), rand_index[n,k], :]) * s : x*s
// x[n,ch,:] read once; k>=0 branch is wave-uniform (no divergence).
// ---------------------------------------------------------------------------
__global__ __launch_bounds__(256) void shuffle_out_fused(
    const float4* __restrict__ x4, const float* __restrict__ s_ca,
    const int* __restrict__ rand_index, const int* __restrict__ partner,
    const int* __restrict__ rank, float4* __restrict__ out4) {
  const unsigned int lane = threadIdx.x & 63u;
  const unsigned int pw = blockIdx.x * 4u + (threadIdx.x >> 6);  // (n,ch) id
  const unsigned int n = pw >> 11;
  const unsigned int ch = pw & 2047u;
  const unsigned int g = n >> 4;   // way group
  const unsigned int b = n & 15u;  // index within group

  // out m-index: plain = g*32 + b, aug = g*32 + 16 + b
  const size_t out_plain =
      (((size_t)((g << 5) | b) * C_CH + ch) << 6) | lane;
  const size_t out_aug = out_plain + ((size_t)(16 * C_CH) << 6);

  const float s = s_ca[pw];                       // wave-uniform
  const float4 v = x4[((size_t)pw << 6) | lane];  // coalesced 16B/lane
  float4 pv = make_float4(v.x * s, v.y * s, v.z * s, v.w * s);
  float4 av = pv;

  const int k = rank[pw];  // wave-uniform
  if (k >= 0) {            // wave-uniform branch
    int jn = (int)n + 1 + partner[n];
    if (jn >= N_SAMP) jn -= N_SAMP;
    const int pc = rand_index[(size_t)n * S_TOP + k];
    const float4 u = x4[((((size_t)jn << 11) | (size_t)pc) << 6) | lane];
    av.x = (0.7f * v.x + 0.3f * u.x) * s;
    av.y = (0.7f * v.y + 0.3f * u.y) * s;
    av.z = (0.7f * v.z + 0.3f * u.z) * s;
    av.w = (0.7f * v.w + 0.3f * u.w) * s;
  }

  out4[out_plain] = pv;
  out4[out_aug] = av;
}

extern "C" void kernel_launch(void* const* d_in, const int* in_sizes, int n_in,
                              void* d_out, int out_size, void* d_ws,
                              size_t ws_size, hipStream_t stream) {
  const float* x = (const float*)d_in[0];
  const float* s_ca = (const float*)d_in[1];
  const int* rand_index = (const int*)d_in[2];
  const int* partner = (const int*)d_in[3];
  // d_in[4] = shuffle_num (512, fixed by setup)

  int* rank = (int*)d_ws;  // N_SAMP * C_CH ints = 655,360 B

  rank_lds_kernel<<<N_SAMP * 8, 256, 0, stream>>>(s_ca, rank);

  // One wave per (n, ch): 80*2048 = 163,840 waves = 40,960 blocks of 256.
  const int nblocks = (N_SAMP * C_CH) / 4;
  shuffle_out_fused<<<nblocks, 256, 0, stream>>>(
      (const float4*)x, s_ca, rand_index, partner, rank, (float4*)d_out);
}

// Round 4
// 459.118 us; speedup vs baseline: 1.2230x; 1.0413x over previous
//
#include <hip/hip_runtime.h>

// Problem constants (fixed by setup_inputs).
#define N_SAMP 80
#define C_CH   2048
#define HW     256          // 16*16
#define S_TOP  512
#define HW4    64           // HW / 4 (float4 per channel)

// ---------------------------------------------------------------------------
// Single fused kernel. Each 64-lane wave owns ONE (n, ch) pair and:
//
//  1. Computes ch's top-k rank IN-WAVE via ballot-counting:
//       rank(ch) = #{ j : s_j > s_ch } + #{ j : s_j == s_ch && j < ch }
//     (exact jax.lax.top_k semantics: value desc, index asc on ties; scores
//     are uniform[0,1) floats -> no NaN / -0 concerns).
//     s_ch (si) is WAVE-UNIFORM, so lane l tests 32 channels (8 coalesced
//     float4 loads of the 8KB s_ca row, L1-resident after the block's first
//     wave) and each test is one __ballot; __popcll accumulates the count
//     into an SGPR. No LDS, no wave reduction, no separate rank kernel.
//
//  2. Produces BOTH output rows:
//       plain: x[n,ch,:] * s
//       aug  : rank < 512 ? (0.7*x[n,ch,:] + 0.3*x[jn, rand_index[n,rank],:])*s
//                         : x[n,ch,:] * s
//     x[n,ch,:] read once; the rank<512 branch is wave-uniform; rank is a
//     scalar so the rand_index load is scalar too.
//
// Total ballot work (80*2048^2 compares ~ 17 us of VALU across the chip) is
// hidden under the memory-bound stream (~545 MB HBM min).
// ---------------------------------------------------------------------------
__global__ __launch_bounds__(256) void fused_shuffle_kernel(
    const float4* __restrict__ x4, const float* __restrict__ s_ca,
    const int* __restrict__ rand_index, const int* __restrict__ partner,
    float4* __restrict__ out4) {
  const unsigned int lane = threadIdx.x & 63u;
  const unsigned int pw = blockIdx.x * 4u + (threadIdx.x >> 6);  // (n,ch) id
  const unsigned int n = pw >> 11;
  const unsigned int ch = pw & 2047u;
  const unsigned int g = n >> 4;   // way group
  const unsigned int b = n & 15u;  // index within group

  // out m-index: plain = g*32 + b, aug = g*32 + 16 + b
  const size_t out_plain =
      (((size_t)((g << 5) | b) * C_CH + ch) << 6) | lane;
  const size_t out_aug = out_plain + ((size_t)(16 * C_CH) << 6);

  const float* __restrict__ row = s_ca + (size_t)n * C_CH;
  const float si = row[ch];  // score == output scale (wave-uniform value)

  // Main x load — issue early so it overlaps the rank scan.
  const float4 v = x4[((size_t)pw << 6) | lane];

  // Wave-cooperative rank count. Lane l covers channels 4*(q*64+l)+e,
  // q=0..7, e=0..3 — coalesced float4 loads, all 2048 channels exactly once.
  const float4* __restrict__ row4 = (const float4*)row;
  int cnt = 0;
#pragma unroll
  for (int q = 0; q < 8; ++q) {
    const float4 sv = row4[q * 64 + lane];
    const unsigned int j0 = 4u * (q * 64u + lane);
    cnt += __popcll(__ballot(sv.x > si || (sv.x == si && (j0 + 0u) < ch)));
    cnt += __popcll(__ballot(sv.y > si || (sv.y == si && (j0 + 1u) < ch)));
    cnt += __popcll(__ballot(sv.z > si || (sv.z == si && (j0 + 2u) < ch)));
    cnt += __popcll(__ballot(sv.w > si || (sv.w == si && (j0 + 3u) < ch)));
  }

  float4 pv = make_float4(v.x * si, v.y * si, v.z * si, v.w * si);
  float4 av = pv;

  if (cnt < S_TOP) {  // wave-uniform branch; cnt is the topk position k
    int jn = (int)n + 1 + partner[n];
    if (jn >= N_SAMP) jn -= N_SAMP;
    const int pc = rand_index[(size_t)n * S_TOP + cnt];  // scalar load
    const float4 u = x4[((((size_t)jn << 11) | (size_t)pc) << 6) | lane];
    av.x = (0.7f * v.x + 0.3f * u.x) * si;
    av.y = (0.7f * v.y + 0.3f * u.y) * si;
    av.z = (0.7f * v.z + 0.3f * u.z) * si;
    av.w = (0.7f * v.w + 0.3f * u.w) * si;
  }

  out4[out_plain] = pv;
  out4[out_aug] = av;
}

extern "C" void kernel_launch(void* const* d_in, const int* in_sizes, int n_in,
                              void* d_out, int out_size, void* d_ws,
                              size_t ws_size, hipStream_t stream) {
  const float* x = (const float*)d_in[0];
  const float* s_ca = (const float*)d_in[1];
  const int* rand_index = (const int*)d_in[2];
  const int* partner = (const int*)d_in[3];
  // d_in[4] = shuffle_num (512, fixed by setup); d_ws unused now.

  // One wave per (n, ch): 80*2048 = 163,840 waves = 40,960 blocks of 256.
  const int nblocks = (N_SAMP * C_CH) / 4;
  fused_shuffle_kernel<<<nblocks, 256, 0, stream>>>(
      (const float4*)x, s_ca, rand_index, partner, (float4*)d_out);
}

// Round 5
// 445.658 us; speedup vs baseline: 1.2600x; 1.0302x over previous
//
#include <hip/hip_runtime.h>

// Problem constants (fixed by setup_inputs).
#define N_SAMP 80
#define C_CH   2048
#define HW     256          // 16*16
#define S_TOP  512
#define HW4    64           // HW / 4 (float4 per channel)

// ---------------------------------------------------------------------------
// Single fused kernel, 4 channels per wave.
//
// Block = 256 threads = 4 waves; block covers 16 consecutive channels of one
// row n; wave w owns channels ch0 = chunk*16 + w*4 .. +3.
//
// Rank via ballot-counting with u64 packed keys (exact jax.lax.top_k
// semantics, same key as the verified sort/count kernels):
//   key(j) = (monotone(score bits) << 11) | (2047 - j)
//   rank(ch) = #{ j : key(j) > key(ch) }   (keys unique; desc value,
//                                           asc index on ties)
// Element keys are built ONCE per scanned element and reused across the
// wave's 4 channels -> one v_cmp_gt_u64 + s_popc per (element, channel).
// The 8 coalesced float4 scan loads of the 8KB s_ca row now serve 8KB of
// output (4x amortization vs round 4); wave count drops 163,840 -> 40,960.
//
// Outputs per channel c (aug branch is wave-uniform; rank k is scalar so
// rand_index is a scalar load):
//   plain: x[n,c,:] * s
//   aug  : k<512 ? (0.7*x[n,c,:] + 0.3*x[jn, rand_index[n,k], :]) * s : plain
// ---------------------------------------------------------------------------
__global__ __launch_bounds__(256) void fused_shuffle_kernel(
    const float4* __restrict__ x4, const float* __restrict__ s_ca,
    const int* __restrict__ rand_index, const int* __restrict__ partner,
    float4* __restrict__ out4) {
  const unsigned int lane = threadIdx.x & 63u;
  const unsigned int wid = threadIdx.x >> 6;       // 0..3
  const unsigned int blk = blockIdx.x;             // 0..10239
  const unsigned int n = blk >> 7;                 // row
  const unsigned int ch0 = ((blk & 127u) << 4) | (wid << 2);
  const unsigned int g = n >> 4;   // way group
  const unsigned int b = n & 15u;  // index within group

  const float* __restrict__ row = s_ca + (size_t)n * C_CH;
  const float4* __restrict__ row4 = (const float4*)row;

  // Scores for this wave's 4 channels (ch0 % 4 == 0 -> one float4).
  const float4 sq = row4[ch0 >> 2];
  const float si[4] = {sq.x, sq.y, sq.z, sq.w};

  // Partner row (scalar) — issue early.
  int jn = (int)n + 1 + partner[n];
  if (jn >= N_SAMP) jn -= N_SAMP;

  // Main x rows — issue before the scan so they overlap it.
  float4 v[4];
#pragma unroll
  for (int c = 0; c < 4; ++c)
    v[c] = x4[(((size_t)n * C_CH + ch0 + c) << 6) | lane];

  // Packed keys for the 4 owned channels.
  unsigned long long kc[4];
#pragma unroll
  for (int c = 0; c < 4; ++c) {
    unsigned int bi = __float_as_uint(si[c]);
    bi ^= (bi & 0x80000000u) ? 0xFFFFFFFFu : 0x80000000u;
    kc[c] = ((unsigned long long)bi << 11) |
            (unsigned long long)(C_CH - 1 - (ch0 + c));
  }

  // Wave-cooperative rank scan: lane covers elements 4*(q*64+lane)+e.
  int cnt[4] = {0, 0, 0, 0};
#pragma unroll
  for (int q = 0; q < 8; ++q) {
    const float4 sv = row4[q * 64 + lane];
    const unsigned int j0 = 4u * (q * 64u + lane);
    unsigned long long kj[4];
#pragma unroll
    for (int e = 0; e < 4; ++e) {
      unsigned int bj = __float_as_uint((&sv.x)[e]);
      bj ^= (bj & 0x80000000u) ? 0xFFFFFFFFu : 0x80000000u;
      kj[e] = ((unsigned long long)bj << 11) |
              (unsigned long long)(C_CH - 1 - (j0 + e));
    }
#pragma unroll
    for (int c = 0; c < 4; ++c) {
#pragma unroll
      for (int e = 0; e < 4; ++e)
        cnt[c] += __popcll(__ballot(kj[e] > kc[c]));
    }
  }

  // Output bases (float4 units): plain m = g*32+b, aug m = g*32+16+b.
  const size_t base_plain =
      (((size_t)((g << 5) | b) * C_CH + ch0) << 6) | lane;
  const size_t aug_off = ((size_t)(16 * C_CH)) << 6;

#pragma unroll
  for (int c = 0; c < 4; ++c) {
    const float s = si[c];
    float4 pv = make_float4(v[c].x * s, v[c].y * s, v[c].z * s, v[c].w * s);
    float4 av = pv;
    if (cnt[c] < S_TOP) {  // wave-uniform; cnt[c] is topk position k
      const int pc = rand_index[(size_t)n * S_TOP + cnt[c]];  // scalar load
      const float4 u = x4[((((size_t)jn << 11) | (size_t)pc) << 6) | lane];
      av.x = (0.7f * v[c].x + 0.3f * u.x) * s;
      av.y = (0.7f * v[c].y + 0.3f * u.y) * s;
      av.z = (0.7f * v[c].z + 0.3f * u.z) * s;
      av.w = (0.7f * v[c].w + 0.3f * u.w) * s;
    }
    out4[base_plain + ((size_t)c << 6)] = pv;
    out4[base_plain + aug_off + ((size_t)c << 6)] = av;
  }
}

extern "C" void kernel_launch(void* const* d_in, const int* in_sizes, int n_in,
                              void* d_out, int out_size, void* d_ws,
                              size_t ws_size, hipStream_t stream) {
  const float* x = (const float*)d_in[0];
  const float* s_ca = (const float*)d_in[1];
  const int* rand_index = (const int*)d_in[2];
  const int* partner = (const int*)d_in[3];
  // d_in[4] = shuffle_num (512, fixed by setup); d_ws unused.

  // 4 waves/block x 4 channels/wave = 16 channels/block:
  // 80 * 2048 / 16 = 10,240 blocks.
  const int nblocks = (N_SAMP * C_CH) / 16;
  fused_shuffle_kernel<<<nblocks, 256, 0, stream>>>(
      (const float4*)x, s_ca, rand_index, partner, (float4*)d_out);
}